// Round 8
// baseline (178.699 us; speedup 1.0000x reference)
//
#include <hip/hip_runtime.h>

using f32x4  = __attribute__((ext_vector_type(4))) float;
using bf16x8 = __attribute__((ext_vector_type(8))) __bf16;

#define SB() __builtin_amdgcn_sched_barrier(0)

// ---------- helpers ----------
__device__ __forceinline__ unsigned short f2bf(float f) {
  unsigned int u = __builtin_bit_cast(unsigned int, f);
  u = (u + 0x7FFFu + ((u >> 16) & 1u)) >> 16;   // RNE
  return (unsigned short)u;
}

__device__ __forceinline__ void g2lds16(const void* g, void* l) {
  __builtin_amdgcn_global_load_lds(
      (const __attribute__((address_space(1))) void*)g,
      (__attribute__((address_space(3))) void*)l, 16, 0, 0);
}

// ---------- fused prep: W cast + A repack + B repack + router/x-cast ----------
__global__ __launch_bounds__(256) void k_pre(const float* __restrict__ W,
                                             const float* __restrict__ A,
                                             const float* __restrict__ Bexp,
                                             const float* __restrict__ x,
                                             const float* __restrict__ Wr,
                                             unsigned short* __restrict__ Wb,
                                             unsigned short* __restrict__ Ab,
                                             unsigned short* __restrict__ Bb,
                                             unsigned short* __restrict__ xb,
                                             float* __restrict__ wout) {
  int b = blockIdx.x;
  if (b < 2048) {                       // W cast
    int t = b * 256 + threadIdx.x;
    const float4* p = (const float4*)W;
    float4 a = p[2 * t], c = p[2 * t + 1];
    uint4 o;
    o.x = (unsigned)f2bf(a.x) | ((unsigned)f2bf(a.y) << 16);
    o.y = (unsigned)f2bf(a.z) | ((unsigned)f2bf(a.w) << 16);
    o.z = (unsigned)f2bf(c.x) | ((unsigned)f2bf(c.y) << 16);
    o.w = (unsigned)f2bf(c.z) | ((unsigned)f2bf(c.w) << 16);
    ((uint4*)Wb)[t] = o;
    return;
  }
  if (b < 3072) {                       // A (E,D,R) -> Ab[j=e*16+r][d]
    int t = (b - 2048) * 256 + threadIdx.x;
    int j = t >> 11, d = t & 2047;
    Ab[t] = f2bf(A[((size_t)(j >> 4) * 2048 + d) * 16 + (j & 15)]);
    return;
  }
  if (b < 4096) {                       // Bexp (E,R,O) -> Bb[o][j=e*16+r]
    int t = (b - 3072) * 256 + threadIdx.x;
    int j = t >> 11, o = t & 2047;
    Bb[(size_t)o * 128 + j] = f2bf(Bexp[(size_t)(j >> 4) * 32768 + (j & 15) * 2048 + o]);
    return;
  }
  // router (f32 exact) + x -> bf16 cast
  int tok  = (b - 4096) * 4 + (threadIdx.x >> 6);
  int lane = threadIdx.x & 63;
  const float4* xr = (const float4*)(x + (size_t)tok * 2048);
  float4 xv[8];
#pragma unroll
  for (int c = 0; c < 8; c++) xv[c] = xr[c * 64 + lane];
  uint2* xbr = (uint2*)(xb + (size_t)tok * 2048);
#pragma unroll
  for (int c = 0; c < 8; c++) {
    uint2 o;
    o.x = (unsigned)f2bf(xv[c].x) | ((unsigned)f2bf(xv[c].y) << 16);
    o.y = (unsigned)f2bf(xv[c].z) | ((unsigned)f2bf(xv[c].w) << 16);
    xbr[c * 64 + lane] = o;
  }
  float lg[8];
#pragma unroll
  for (int e = 0; e < 8; e++) {
    const float4* wr = (const float4*)(Wr + e * 2048);
    float p = 0.f;
#pragma unroll
    for (int c = 0; c < 8; c++) {
      float4 wv = wr[c * 64 + lane];
      p += xv[c].x * wv.x + xv[c].y * wv.y + xv[c].z * wv.z + xv[c].w * wv.w;
    }
#pragma unroll
    for (int off = 32; off; off >>= 1) p += __shfl_xor(p, off);
    lg[e] = p;
  }
  int i1 = 0;
#pragma unroll
  for (int e = 1; e < 8; e++) if (lg[e] > lg[i1]) i1 = e;
  int i2 = (i1 == 0) ? 1 : 0;
#pragma unroll
  for (int e = 0; e < 8; e++) { if (e == i1) continue; if (lg[e] > lg[i2]) i2 = e; }
  float e2 = expf(lg[i2] - lg[i1]);
  float den = 1.f + e2;
  if (lane < 8) wout[(size_t)tok * 8 + lane] =
      (lane == i1) ? (1.f / den) : ((lane == i2) ? (e2 / den) : 0.f);
}

// ---------- LoRA-down GEMM (32x128 tile, 256 blocks) ----------
__global__ __launch_bounds__(256) void k_gemm_lora(const unsigned short* __restrict__ xb,
                                                   const unsigned short* __restrict__ Ab,
                                                   const float* __restrict__ wrt,
                                                   unsigned short* __restrict__ tmat) {
  __shared__ unsigned short lsA[32 * 64];
  __shared__ unsigned short lsB[128 * 64];
  const int w = threadIdx.x >> 6, lane = threadIdx.x & 63;
  const int mBase = blockIdx.y * 32;
  const int rl = lane & 15, kq = lane >> 4;
  const unsigned short* aS;
  const unsigned short* bS[4];
  {
    int r  = w * 8 + (lane >> 3);
    int cg = (lane & 7) ^ (r & 7);
    aS = xb + (size_t)(mBase + r) * 2048 + cg * 8;
  }
#pragma unroll
  for (int q = 0; q < 4; ++q) {
    int r  = (w * 4 + q) * 8 + (lane >> 3);
    int cg = (lane & 7) ^ (r & 7);
    bS[q] = Ab + (size_t)r * 2048 + cg * 8;
  }
  f32x4 z = {0.f, 0.f, 0.f, 0.f};
  f32x4 acc[2][2];
#pragma unroll
  for (int i = 0; i < 2; i++)
#pragma unroll
    for (int j = 0; j < 2; j++) acc[i][j] = z;

  for (int s = 0; s < 32; ++s) {
    g2lds16(aS, (char*)lsA + w * 1024);
    aS += 64;
#pragma unroll
    for (int q = 0; q < 4; ++q) {
      g2lds16(bS[q], (char*)lsB + (w * 4 + q) * 1024);
      bS[q] += 64;
    }
    __syncthreads();
#pragma unroll
    for (int kk = 0; kk < 2; ++kk) {
      bf16x8 af[2], bv[2];
#pragma unroll
      for (int i = 0; i < 2; ++i) {
        int r = i * 16 + rl;
        int c = (kk * 4 + kq) ^ (r & 7);
        af[i] = *(const bf16x8*)((const char*)lsA + r * 128 + c * 16);
      }
#pragma unroll
      for (int j = 0; j < 2; ++j) {
        int r = w * 32 + j * 16 + rl;
        int c = (kk * 4 + kq) ^ (r & 7);
        bv[j] = *(const bf16x8*)((const char*)lsB + r * 128 + c * 16);
      }
#pragma unroll
      for (int i = 0; i < 2; ++i)
#pragma unroll
        for (int j = 0; j < 2; ++j)
          acc[i][j] = __builtin_amdgcn_mfma_f32_16x16x32_bf16(af[i], bv[j], acc[i][j], 0, 0, 0);
    }
    __syncthreads();
  }
#pragma unroll
  for (int j = 0; j < 2; ++j) {
    int jj = w * 32 + j * 16 + rl;
    int e  = jj >> 4;
#pragma unroll
    for (int i = 0; i < 2; ++i) {
      int m0 = mBase + i * 16 + kq * 4;
#pragma unroll
      for (int q = 0; q < 4; ++q) {
        int m = m0 + q;
        tmat[(size_t)m * 128 + jj] = f2bf(acc[i][j][q] * wrt[(size_t)m * 8 + e]);
      }
    }
  }
}

// ---------- main GEMM: 256x256, BK=64, 2 dbufs, 4 k-sliced phases, counted vmcnt ----------
// out = xb.Wb^T (K=2048, tiles 0..31) ++ tmat.Bb^T (K=128, tiles 32..33) + bias
__global__ __launch_bounds__(512, 1) void k_gemm_main(const unsigned short* __restrict__ xb,
                                                      const unsigned short* __restrict__ Wb,
                                                      const unsigned short* __restrict__ tm,
                                                      const unsigned short* __restrict__ Bb,
                                                      const float* __restrict__ bias,
                                                      float* __restrict__ out) {
  // LDS: A[d][ks][256r][32c] = 2*2*16KB = 64KB @0 ; B same @65536. 128 KiB total.
  __shared__ unsigned short lds[65536];
  char* L = (char*)lds;
  const int tid = threadIdx.x, wid = tid >> 6, lane = tid & 63;
  const int wm = wid >> 2, wn = wid & 3;            // 2M x 4N; wave tile 128 x 64
  const int bid = blockIdx.x;
  const int s = (bid & 7) * 32 + (bid >> 3);        // XCD swizzle (256 = 8*32, bijective)
  const int mBase = (s >> 3) * 256;
  const int nBase = (s & 7) * 256;
  const int rl = lane & 15, kq = lane >> 4;
  // ds_read base offsets (64B rows, 4 chunks, chunk ^= row&3 -> distinct-slot, conflict-free)
  const int cswz  = ((kq ^ (rl & 3)) << 4);
  const int aBase = wm * 8192 + rl * 64 + cswz;               // + d*32768 + ks*16384 + mi*1024
  const int bBase = 65536 + wn * 4096 + rl * 64 + cswz;       // + d*32768 + ks*16384 + nh*2048 + nj*1024

  // staging: half-tile = 256 rows x 32 cols (16KB); 2 ops x 512thr x 16B
  const int r8 = tid >> 2;                                    // 0..127 (op adds +128)
  const int c4 = tid & 3;
  const int scol = ((c4 ^ (r8 & 3)) << 3);                    // pre-swizzled src chunk (elems)
  const unsigned short* pA[2];
  const unsigned short* pB[2];
#pragma unroll
  for (int o = 0; o < 2; ++o) {
    pA[o] = xb + (size_t)(mBase + o * 128 + r8) * 2048 + scol;
    pB[o] = Wb + (size_t)(nBase + o * 128 + r8) * 2048 + scol;
  }
  const int dstBase = r8 * 64 + c4 * 16;

  auto stageHT = [&](int tau, int mtx, int ks) {               // one half-tile (2 loads/thread)
    if (tau >= 34) return;
    const int dst = mtx * 65536 + (tau & 1) * 32768 + ks * 16384 + dstBase;
    if (tau < 32) {
      const int off = tau * 64 + ks * 32;
      const unsigned short* p0 = mtx ? pB[0] : pA[0];
      const unsigned short* p1 = mtx ? pB[1] : pA[1];
      g2lds16(p0 + off, L + dst);
      g2lds16(p1 + off, L + dst + 8192);
    } else {
      const int off = (tau - 32) * 64 + ks * 32;
      const unsigned short* q0 = mtx ? (Bb + (size_t)(nBase + r8) * 128 + scol)
                                     : (tm + (size_t)(mBase + r8) * 128 + scol);
      const unsigned short* q1 = mtx ? (Bb + (size_t)(nBase + 128 + r8) * 128 + scol)
                                     : (tm + (size_t)(mBase + 128 + r8) * 128 + scol);
      g2lds16(q0 + off, L + dst);
      g2lds16(q1 + off, L + dst + 8192);
    }
  };

  f32x4 z = {0.f, 0.f, 0.f, 0.f};
  f32x4 acc[8][4];
#pragma unroll
  for (int i = 0; i < 8; ++i)
#pragma unroll
    for (int j = 0; j < 4; ++j) acc[i][j] = z;

  // prologue: tile 0 fully, in steady slot order; allow khi in flight
  stageHT(0, 0, 0); stageHT(0, 1, 0); stageHT(0, 0, 1); stageHT(0, 1, 1);
  SB(); asm volatile("s_waitcnt vmcnt(4)" ::: "memory");
  __builtin_amdgcn_s_barrier(); SB();

#define MFMA16(NH)                                                                    \
  do {                                                                                \
    __builtin_amdgcn_s_setprio(1);                                                    \
    _Pragma("unroll")                                                                 \
    for (int mi_ = 0; mi_ < 8; ++mi_) {                                               \
      _Pragma("unroll")                                                               \
      for (int nj_ = 0; nj_ < 2; ++nj_)                                               \
        acc[mi_][(NH)*2 + nj_] = __builtin_amdgcn_mfma_f32_16x16x32_bf16(             \
            af[mi_], bv[(NH)*2 + nj_], acc[mi_][(NH)*2 + nj_], 0, 0, 0);              \
    }                                                                                 \
    __builtin_amdgcn_s_setprio(0);                                                    \
  } while (0)

#pragma unroll 2
  for (int t = 0; t < 34; ++t) {
    const int d = t & 1;
    const char* bA = L + d * 32768;
    const char* bB = L + d * 32768;
    bf16x8 af[8], bv[4];
    // ---- ph0: ks0, n-lo. reads 10; stage A-klo(t+1)
#pragma unroll
    for (int mi = 0; mi < 8; ++mi) af[mi] = *(const bf16x8*)(bA + aBase + mi * 1024);
#pragma unroll
    for (int nj = 0; nj < 2; ++nj) bv[nj] = *(const bf16x8*)(bB + bBase + nj * 1024);
    stageHT(t + 1, 0, 0);
    SB(); __builtin_amdgcn_s_barrier(); SB();
    asm volatile("s_waitcnt lgkmcnt(0)" ::: "memory"); SB();
    MFMA16(0);
    // ---- ph1: ks0, n-hi. reads 2; stage B-klo(t+1); vm covers khi(t)
#pragma unroll
    for (int nj = 0; nj < 2; ++nj) bv[2 + nj] = *(const bf16x8*)(bB + bBase + 2048 + nj * 1024);
    stageHT(t + 1, 1, 0);
    SB();
    if (t < 33) asm volatile("s_waitcnt vmcnt(4)" ::: "memory");
    else        asm volatile("s_waitcnt vmcnt(0)" ::: "memory");
    __builtin_amdgcn_s_barrier(); SB();
    asm volatile("s_waitcnt lgkmcnt(0)" ::: "memory"); SB();
    MFMA16(1);
    // ---- ph2: ks1, n-lo. reads 10; stage A-khi(t+1)
#pragma unroll
    for (int mi = 0; mi < 8; ++mi) af[mi] = *(const bf16x8*)(bA + 16384 + aBase + mi * 1024);
#pragma unroll
    for (int nj = 0; nj < 2; ++nj) bv[nj] = *(const bf16x8*)(bB + 16384 + bBase + nj * 1024);
    stageHT(t + 1, 0, 1);
    SB(); __builtin_amdgcn_s_barrier(); SB();
    asm volatile("s_waitcnt lgkmcnt(0)" ::: "memory"); SB();
    MFMA16(0);
    // ---- ph3: ks1, n-hi. reads 2; stage B-khi(t+1); vm covers klo(t+1)
#pragma unroll
    for (int nj = 0; nj < 2; ++nj) bv[2 + nj] = *(const bf16x8*)(bB + 16384 + bBase + 2048 + nj * 1024);
    stageHT(t + 1, 1, 1);
    SB();
    if (t < 33) asm volatile("s_waitcnt vmcnt(4)" ::: "memory");
    __builtin_amdgcn_s_barrier(); SB();
    asm volatile("s_waitcnt lgkmcnt(0)" ::: "memory"); SB();
    MFMA16(1);
  }
#undef MFMA16

#pragma unroll
  for (int nj = 0; nj < 4; ++nj) {
    int o = nBase + wn * 64 + nj * 16 + rl;
    float bb = bias[o];
#pragma unroll
    for (int mi = 0; mi < 8; ++mi) {
      int m0 = mBase + wm * 128 + mi * 16 + kq * 4;
#pragma unroll
      for (int q = 0; q < 4; ++q)
        out[(size_t)(m0 + q) * 2048 + o] = acc[mi][nj][q] + bb;
    }
  }
}

extern "C" void kernel_launch(void* const* d_in, const int* in_sizes, int n_in,
                              void* d_out, int out_size, void* d_ws, size_t ws_size,
                              hipStream_t stream) {
  const float* x    = (const float*)d_in[0];   // (4,2048,2048)
  const float* W    = (const float*)d_in[1];   // (2048,2048)
  const float* bias = (const float*)d_in[2];   // (2048)
  const float* Wr   = (const float*)d_in[3];   // (8,2048)
  const float* A    = (const float*)d_in[4];   // (8,2048,16)
  const float* Bexp = (const float*)d_in[5];   // (8,16,2048)
  float* out = (float*)d_out;

  char* ws = (char*)d_ws;
  unsigned short* xb = (unsigned short*)(ws);                 // 33,554,432 B
  unsigned short* Wb = (unsigned short*)(ws + 33554432);      //  8,388,608 B
  unsigned short* Ab = (unsigned short*)(ws + 41943040);      //    524,288 B
  unsigned short* Bb = (unsigned short*)(ws + 42467328);      //    524,288 B
  unsigned short* tm = (unsigned short*)(ws + 42991616);      //  2,097,152 B
  float*          wr = (float*)(ws + 45088768);               //    262,144 B

  (void)in_sizes; (void)n_in; (void)out_size; (void)ws_size;

  k_pre       <<<dim3(6144), 256, 0, stream>>>(W, A, Bexp, x, Wr, Wb, Ab, Bb, xb, wr);
  k_gemm_lora <<<dim3(1, 256), 256, 0, stream>>>(xb, Ab, wr, tm);
  k_gemm_main <<<dim3(256), 512, 0, stream>>>(xb, Wb, tm, Bb, bias, out);
}

// Round 9
// 161.734 us; speedup vs baseline: 1.1049x; 1.1049x over previous
//
#include <hip/hip_runtime.h>

using f32x4  = __attribute__((ext_vector_type(4))) float;
using bf16x8 = __attribute__((ext_vector_type(8))) __bf16;

#define SB() __builtin_amdgcn_sched_barrier(0)

// ---------- helpers ----------
__device__ __forceinline__ unsigned short f2bf(float f) {
  unsigned int u = __builtin_bit_cast(unsigned int, f);
  u = (u + 0x7FFFu + ((u >> 16) & 1u)) >> 16;   // RNE
  return (unsigned short)u;
}

__device__ __forceinline__ void g2lds16(const void* g, void* l) {
  __builtin_amdgcn_global_load_lds(
      (const __attribute__((address_space(1))) void*)g,
      (__attribute__((address_space(3))) void*)l, 16, 0, 0);
}

// ---------- fused prep: W cast + A repack + B repack + router(4tok/wave)/x-cast ----------
__global__ __launch_bounds__(256) void k_pre(const float* __restrict__ W,
                                             const float* __restrict__ A,
                                             const float* __restrict__ Bexp,
                                             const float* __restrict__ x,
                                             const float* __restrict__ Wr,
                                             unsigned short* __restrict__ Wb,
                                             unsigned short* __restrict__ Ab,
                                             unsigned short* __restrict__ Bb,
                                             unsigned short* __restrict__ xb,
                                             float* __restrict__ wout) {
  int b = blockIdx.x;
  if (b < 2048) {                       // W cast
    int t = b * 256 + threadIdx.x;
    const float4* p = (const float4*)W;
    float4 a = p[2 * t], c = p[2 * t + 1];
    uint4 o;
    o.x = (unsigned)f2bf(a.x) | ((unsigned)f2bf(a.y) << 16);
    o.y = (unsigned)f2bf(a.z) | ((unsigned)f2bf(a.w) << 16);
    o.z = (unsigned)f2bf(c.x) | ((unsigned)f2bf(c.y) << 16);
    o.w = (unsigned)f2bf(c.z) | ((unsigned)f2bf(c.w) << 16);
    ((uint4*)Wb)[t] = o;
    return;
  }
  if (b < 3072) {                       // A (E,D,R) -> Ab[j=e*16+r][d]
    int t = (b - 2048) * 256 + threadIdx.x;
    int j = t >> 11, d = t & 2047;
    Ab[t] = f2bf(A[((size_t)(j >> 4) * 2048 + d) * 16 + (j & 15)]);
    return;
  }
  if (b < 4096) {                       // Bexp (E,R,O) -> Bb[o][j=e*16+r]
    int t = (b - 3072) * 256 + threadIdx.x;
    int j = t >> 11, o = t & 2047;
    Bb[(size_t)o * 128 + j] = f2bf(Bexp[(size_t)(j >> 4) * 32768 + (j & 15) * 2048 + o]);
    return;
  }
  // router (f32 exact) + x-cast: 16 tokens/block, 4 per wave (Wr stream amortized 4x)
  int wvi  = threadIdx.x >> 6, lane = threadIdx.x & 63;
  int tok0 = (b - 4096) * 16 + wvi * 4;
  const float4* xr[4];
  uint2* xbw[4];
#pragma unroll
  for (int tk = 0; tk < 4; ++tk) {
    xr[tk]  = (const float4*)(x + (size_t)(tok0 + tk) * 2048);
    xbw[tk] = (uint2*)(xb + (size_t)(tok0 + tk) * 2048);
  }
  float lg[4][8];
#pragma unroll
  for (int tk = 0; tk < 4; ++tk)
#pragma unroll
    for (int e = 0; e < 8; ++e) lg[tk][e] = 0.f;
#pragma unroll
  for (int c = 0; c < 8; ++c) {
    float4 xv[4];
#pragma unroll
    for (int tk = 0; tk < 4; ++tk) {
      xv[tk] = xr[tk][c * 64 + lane];
      uint2 o;
      o.x = (unsigned)f2bf(xv[tk].x) | ((unsigned)f2bf(xv[tk].y) << 16);
      o.y = (unsigned)f2bf(xv[tk].z) | ((unsigned)f2bf(xv[tk].w) << 16);
      xbw[tk][c * 64 + lane] = o;
    }
#pragma unroll
    for (int e = 0; e < 8; ++e) {
      float4 wv = ((const float4*)(Wr + e * 2048))[c * 64 + lane];
#pragma unroll
      for (int tk = 0; tk < 4; ++tk)
        lg[tk][e] += xv[tk].x * wv.x + xv[tk].y * wv.y + xv[tk].z * wv.z + xv[tk].w * wv.w;
    }
  }
#pragma unroll
  for (int tk = 0; tk < 4; ++tk) {
#pragma unroll
    for (int e = 0; e < 8; ++e) {
      float p = lg[tk][e];
#pragma unroll
      for (int off = 32; off; off >>= 1) p += __shfl_xor(p, off);
      lg[tk][e] = p;
    }
    int i1 = 0;
#pragma unroll
    for (int e = 1; e < 8; ++e) if (lg[tk][e] > lg[tk][i1]) i1 = e;
    int i2 = (i1 == 0) ? 1 : 0;
#pragma unroll
    for (int e = 0; e < 8; ++e) { if (e == i1) continue; if (lg[tk][e] > lg[tk][i2]) i2 = e; }
    float e2  = expf(lg[tk][i2] - lg[tk][i1]);
    float den = 1.f + e2;
    if (lane < 8) wout[(size_t)(tok0 + tk) * 8 + lane] =
        (lane == i1) ? (1.f / den) : ((lane == i2) ? (e2 / den) : 0.f);
  }
}

// ---------- LoRA-down GEMM: 32x128 tile, 256 blocks, ring-3 + counted vmcnt ----------
__global__ __launch_bounds__(256) void k_gemm_lora(const unsigned short* __restrict__ xb,
                                                   const unsigned short* __restrict__ Ab,
                                                   const float* __restrict__ wrt,
                                                   unsigned short* __restrict__ tmat) {
  __shared__ unsigned short lds[30720];   // 60KB: A 3 bufs x 4KB @0; B 3 x 16KB @12KB
  char* L = (char*)lds;
  const int w = threadIdx.x >> 6, lane = threadIdx.x & 63;
  const int mBase = blockIdx.y * 32;
  const int rl = lane & 15, kq = lane >> 4;
  // strength-reduced staging pointers (+64 elems per K64-tile)
  const unsigned short* aS;
  const unsigned short* bS[4];
  {
    int r  = w * 8 + (lane >> 3);
    int cg = (lane & 7) ^ (r & 7);
    aS = xb + (size_t)(mBase + r) * 2048 + cg * 8;
  }
#pragma unroll
  for (int q = 0; q < 4; ++q) {
    int r  = (w * 4 + q) * 8 + (lane >> 3);
    int cg = (lane & 7) ^ (r & 7);
    bS[q] = Ab + (size_t)r * 2048 + cg * 8;
  }
  const int dA = w * 1024 + lane * 16;

  auto stage = [&](int tau, int buf) {
    if (tau >= 32) return;
    g2lds16(aS + tau * 64, L + buf * 4096 + dA);
#pragma unroll
    for (int q = 0; q < 4; ++q)
      g2lds16(bS[q] + tau * 64, L + 12288 + buf * 16384 + (w * 4 + q) * 1024 + lane * 16);
  };

  f32x4 z = {0.f, 0.f, 0.f, 0.f};
  f32x4 acc[2][2];
#pragma unroll
  for (int i = 0; i < 2; i++)
#pragma unroll
    for (int j = 0; j < 2; j++) acc[i][j] = z;

  stage(0, 0); stage(1, 1);               // 10 ops in flight
  int bR = 0, bSt = 2;

  for (int s = 0; s < 32; ++s) {
    SB();
    if (s < 31) asm volatile("s_waitcnt vmcnt(5)" ::: "memory");
    else        asm volatile("s_waitcnt vmcnt(0)" ::: "memory");
    __builtin_amdgcn_s_barrier(); SB();
    stage(s + 2, bSt);

    const char* lsA = L + bR * 4096;
    const char* lsB = L + 12288 + bR * 16384;
#pragma unroll
    for (int kk = 0; kk < 2; ++kk) {
      bf16x8 af[2], bv[2];
#pragma unroll
      for (int i = 0; i < 2; ++i) {
        int r = i * 16 + rl;
        int c = (kk * 4 + kq) ^ (r & 7);
        af[i] = *(const bf16x8*)(lsA + r * 128 + c * 16);
      }
#pragma unroll
      for (int j = 0; j < 2; ++j) {
        int r = w * 32 + j * 16 + rl;
        int c = (kk * 4 + kq) ^ (r & 7);
        bv[j] = *(const bf16x8*)(lsB + r * 128 + c * 16);
      }
#pragma unroll
      for (int i = 0; i < 2; ++i)
#pragma unroll
        for (int j = 0; j < 2; ++j)
          acc[i][j] = __builtin_amdgcn_mfma_f32_16x16x32_bf16(af[i], bv[j], acc[i][j], 0, 0, 0);
    }
    bR = (bR == 2) ? 0 : bR + 1;
    bSt = (bSt == 2) ? 0 : bSt + 1;
  }
#pragma unroll
  for (int j = 0; j < 2; ++j) {
    int jj = w * 32 + j * 16 + rl;
    int e  = jj >> 4;
#pragma unroll
    for (int i = 0; i < 2; ++i) {
      int m0 = mBase + i * 16 + kq * 4;
#pragma unroll
      for (int q = 0; q < 4; ++q) {
        int m = m0 + q;
        tmat[(size_t)m * 128 + jj] = f2bf(acc[i][j][q] * wrt[(size_t)m * 8 + e]);
      }
    }
  }
}

// ---------- main GEMM: 128x256 tile, BK=32, ring-3 LDS, 2 blocks/CU (R7 exact) ----------
// out = xb.Wb^T (K=2048, tiles 0..63) ++ tmat.Bb^T (K=128, tiles 64..67) + bias
__global__ __launch_bounds__(256, 2) void k_gemm_main(const unsigned short* __restrict__ xb,
                                                      const unsigned short* __restrict__ Wb,
                                                      const unsigned short* __restrict__ tm,
                                                      const unsigned short* __restrict__ Bb,
                                                      const float* __restrict__ bias,
                                                      float* __restrict__ out) {
  __shared__ unsigned short lds[36864];          // 72 KiB: A 3 bufs x 8KB @0; B 3 x 16KB @24KB
  char* L = (char*)lds;
  const int tid = threadIdx.x, wid = tid >> 6, lane = tid & 63;
  const int wm = wid >> 1, wn = wid & 1;         // 2M x 2N waves; wave tile 64 x 128
  const int bid = blockIdx.x;
  const int s = (bid & 7) * 64 + (bid >> 3);     // XCD swizzle (512 = 8*64, bijective)
  const int mBase = (s >> 3) * 128;
  const int nBase = (s & 7) * 256;
  const int rl = lane & 15, kq = lane >> 4;
  // frag offsets: row*64B + chunk*16, chunk = kq ^ ((row>>1)&3)  [0-conflict proven]
  int aOff[4], bOff[8];
#pragma unroll
  for (int i = 0; i < 4; ++i) {
    int r = wm * 64 + i * 16 + rl;
    aOff[i] = r * 64 + ((kq ^ ((r >> 1) & 3)) << 4);
  }
#pragma unroll
  for (int j = 0; j < 8; ++j) {
    int r = wn * 128 + j * 16 + rl;
    bOff[j] = r * 64 + ((kq ^ ((r >> 1) & 3)) << 4);
  }
  // staging: op covers 64 rows x 64B via 256 threads x 16B; linear LDS dest
  const int sRo = tid >> 2;                                    // row within op
  const int sC  = (((tid & 3) ^ ((tid >> 3) & 3)) << 3);       // pre-swizzled src col (elems)

  const unsigned short* aSrc[2];
  const unsigned short* bSrc[4];
#pragma unroll
  for (int o = 0; o < 2; ++o) aSrc[o] = xb + (size_t)(mBase + o * 64 + sRo) * 2048 + sC;
#pragma unroll
  for (int o = 0; o < 4; ++o) bSrc[o] = Wb + (size_t)(nBase + o * 64 + sRo) * 2048 + sC;

  auto stage = [&](int tau, int bufi) {
    if (tau >= 68) return;
    if (tau < 64) {
#pragma unroll
      for (int o = 0; o < 2; ++o) {
        g2lds16(aSrc[o], L + bufi * 8192 + o * 4096 + wid * 1024);
        aSrc[o] += 32;
      }
#pragma unroll
      for (int o = 0; o < 4; ++o) {
        g2lds16(bSrc[o], L + 24576 + bufi * 16384 + o * 4096 + wid * 1024);
        bSrc[o] += 32;
      }
    } else {                                     // K-extension: 4 cold iterations
      int k0 = (tau - 64) * 32;
#pragma unroll
      for (int o = 0; o < 2; ++o)
        g2lds16(tm + (size_t)(mBase + o * 64 + sRo) * 128 + k0 + sC,
                L + bufi * 8192 + o * 4096 + wid * 1024);
#pragma unroll
      for (int o = 0; o < 4; ++o)
        g2lds16(Bb + (size_t)(nBase + o * 64 + sRo) * 128 + k0 + sC,
                L + 24576 + bufi * 16384 + o * 4096 + wid * 1024);
    }
  };

  f32x4 z = {0.f, 0.f, 0.f, 0.f};
  f32x4 acc[4][8];
#pragma unroll
  for (int i = 0; i < 4; ++i)
#pragma unroll
    for (int j = 0; j < 8; ++j) acc[i][j] = z;

  stage(0, 0); stage(1, 1);                      // 12 ops in flight
  int bR = 0, bS = 2;                            // read buf, stage buf

  for (int t = 0; t < 68; ++t) {
    __builtin_amdgcn_sched_barrier(0);
    if (t <= 65) asm volatile("s_waitcnt vmcnt(6)" ::: "memory");   // tile t landed
    else         asm volatile("s_waitcnt vmcnt(0)" ::: "memory");
    __builtin_amdgcn_s_barrier();
    __builtin_amdgcn_sched_barrier(0);
    stage(t + 2, bS);                            // buf (t+2)%3 = (t-1)%3: readers done

    const char* bA = L + bR * 8192;
    const char* bB = L + 24576 + bR * 16384;
    bf16x8 af[4], bv[8];
#pragma unroll
    for (int j = 0; j < 8; ++j) bv[j] = *(const bf16x8*)(bB + bOff[j]);
#pragma unroll
    for (int i = 0; i < 4; ++i) af[i] = *(const bf16x8*)(bA + aOff[i]);
    __builtin_amdgcn_s_setprio(1);
#pragma unroll
    for (int i = 0; i < 4; ++i)
#pragma unroll
      for (int j = 0; j < 8; ++j)
        acc[i][j] = __builtin_amdgcn_mfma_f32_16x16x32_bf16(af[i], bv[j], acc[i][j], 0, 0, 0);
    __builtin_amdgcn_s_setprio(0);

    bR = (bR == 2) ? 0 : bR + 1;
    bS = (bS == 2) ? 0 : bS + 1;
  }

#pragma unroll
  for (int j = 0; j < 8; ++j) {
    int o = nBase + wn * 128 + j * 16 + rl;
    float bb = bias[o];
#pragma unroll
    for (int i = 0; i < 4; ++i) {
      int m0 = mBase + wm * 64 + i * 16 + kq * 4;
#pragma unroll
      for (int q = 0; q < 4; ++q)
        out[(size_t)(m0 + q) * 2048 + o] = acc[i][j][q] + bb;
    }
  }
}

extern "C" void kernel_launch(void* const* d_in, const int* in_sizes, int n_in,
                              void* d_out, int out_size, void* d_ws, size_t ws_size,
                              hipStream_t stream) {
  const float* x    = (const float*)d_in[0];   // (4,2048,2048)
  const float* W    = (const float*)d_in[1];   // (2048,2048)
  const float* bias = (const float*)d_in[2];   // (2048)
  const float* Wr   = (const float*)d_in[3];   // (8,2048)
  const float* A    = (const float*)d_in[4];   // (8,2048,16)
  const float* Bexp = (const float*)d_in[5];   // (8,16,2048)
  float* out = (float*)d_out;

  char* ws = (char*)d_ws;
  unsigned short* xb = (unsigned short*)(ws);                 // 33,554,432 B
  unsigned short* Wb = (unsigned short*)(ws + 33554432);      //  8,388,608 B
  unsigned short* Ab = (unsigned short*)(ws + 41943040);      //    524,288 B
  unsigned short* Bb = (unsigned short*)(ws + 42467328);      //    524,288 B
  unsigned short* tm = (unsigned short*)(ws + 42991616);      //  2,097,152 B
  float*          wr = (float*)(ws + 45088768);               //    262,144 B

  (void)in_sizes; (void)n_in; (void)out_size; (void)ws_size;

  k_pre       <<<dim3(4608), 256, 0, stream>>>(W, A, Bexp, x, Wr, Wb, Ab, Bb, xb, wr);
  k_gemm_lora <<<dim3(1, 256), 256, 0, stream>>>(xb, Ab, wr, tm);
  k_gemm_main <<<dim3(512), 256, 0, stream>>>(xb, Wb, tm, Bb, bias, out);
}

// Round 10
// 115.143 us; speedup vs baseline: 1.5520x; 1.4046x over previous
//
#include <hip/hip_runtime.h>

using f32x4  = __attribute__((ext_vector_type(4))) float;
using bf16x8 = __attribute__((ext_vector_type(8))) __bf16;

#define SB() __builtin_amdgcn_sched_barrier(0)

// ---------- helpers ----------
__device__ __forceinline__ unsigned short f2bf(float f) {
  unsigned int u = __builtin_bit_cast(unsigned int, f);
  u = (u + 0x7FFFu + ((u >> 16) & 1u)) >> 16;   // RNE
  return (unsigned short)u;
}

__device__ __forceinline__ void g2lds16(const void* g, void* l) {
  __builtin_amdgcn_global_load_lds(
      (const __attribute__((address_space(1))) void*)g,
      (__attribute__((address_space(3))) void*)l, 16, 0, 0);
}

// ---------- fused prep: router(LDS-Wr) first, then W cast + A/B repack ----------
__global__ __launch_bounds__(256) void k_pre(const float* __restrict__ W,
                                             const float* __restrict__ A,
                                             const float* __restrict__ Bexp,
                                             const float* __restrict__ x,
                                             const float* __restrict__ Wr,
                                             unsigned short* __restrict__ Wb,
                                             unsigned short* __restrict__ Ab,
                                             unsigned short* __restrict__ Bb,
                                             unsigned short* __restrict__ xb,
                                             float* __restrict__ wout) {
  __shared__ float swr[8192];             // 32 KB: 4 experts x 2048 f32
  int b = blockIdx.x;
  int tid = threadIdx.x;
  if (b < 2048) {
    // router (f32 exact, Wr via LDS) + x -> bf16 cast; 1 token/wave
    int wvi = tid >> 6, lane = tid & 63;
    int tok = b * 4 + wvi;
    const float4* xr = (const float4*)(x + (size_t)tok * 2048);
    float4 xv[8];
#pragma unroll
    for (int c = 0; c < 8; c++) xv[c] = xr[c * 64 + lane];
    uint2* xbw = (uint2*)(xb + (size_t)tok * 2048);
#pragma unroll
    for (int c = 0; c < 8; c++) {
      uint2 o;
      o.x = (unsigned)f2bf(xv[c].x) | ((unsigned)f2bf(xv[c].y) << 16);
      o.y = (unsigned)f2bf(xv[c].z) | ((unsigned)f2bf(xv[c].w) << 16);
      xbw[c * 64 + lane] = o;
    }
    float lg[8];
#pragma unroll
    for (int half = 0; half < 2; ++half) {
      if (half) __syncthreads();                   // protect previous half's readers
      const float4* src = (const float4*)(Wr + half * 4 * 2048);
#pragma unroll
      for (int i = 0; i < 8; ++i) ((float4*)swr)[i * 256 + tid] = src[i * 256 + tid];
      __syncthreads();
#pragma unroll
      for (int e = 0; e < 4; ++e) {
        const float4* wv4 = (const float4*)(swr + e * 2048);
        float p = 0.f;
#pragma unroll
        for (int c = 0; c < 8; ++c) {
          float4 wv = wv4[c * 64 + lane];
          p += xv[c].x * wv.x + xv[c].y * wv.y + xv[c].z * wv.z + xv[c].w * wv.w;
        }
#pragma unroll
        for (int off = 32; off; off >>= 1) p += __shfl_xor(p, off);
        lg[half * 4 + e] = p;
      }
    }
    int i1 = 0;
#pragma unroll
    for (int e = 1; e < 8; e++) if (lg[e] > lg[i1]) i1 = e;
    int i2 = (i1 == 0) ? 1 : 0;
#pragma unroll
    for (int e = 0; e < 8; e++) { if (e == i1) continue; if (lg[e] > lg[i2]) i2 = e; }
    float e2 = expf(lg[i2] - lg[i1]);
    float den = 1.f + e2;
    if (lane < 8) wout[(size_t)tok * 8 + lane] =
        (lane == i1) ? (1.f / den) : ((lane == i2) ? (e2 / den) : 0.f);
    return;
  }
  if (b < 4096) {                       // W cast: (2048,2048) f32 -> bf16, 8/thread
    int t = (b - 2048) * 256 + tid;
    const float4* p = (const float4*)W;
    float4 a = p[2 * t], c = p[2 * t + 1];
    uint4 o;
    o.x = (unsigned)f2bf(a.x) | ((unsigned)f2bf(a.y) << 16);
    o.y = (unsigned)f2bf(a.z) | ((unsigned)f2bf(a.w) << 16);
    o.z = (unsigned)f2bf(c.x) | ((unsigned)f2bf(c.y) << 16);
    o.w = (unsigned)f2bf(c.z) | ((unsigned)f2bf(c.w) << 16);
    ((uint4*)Wb)[t] = o;
    return;
  }
  if (b < 5120) {                       // A (E,D,R) -> Ab[j=e*16+r][d]
    int t = (b - 4096) * 256 + tid;
    int j = t >> 11, d = t & 2047;
    Ab[t] = f2bf(A[((size_t)(j >> 4) * 2048 + d) * 16 + (j & 15)]);
    return;
  }
  {                                     // Bexp (E,R,O) -> Bb[o][j=e*16+r]
    int t = (b - 5120) * 256 + tid;
    int j = t >> 11, o = t & 2047;
    Bb[(size_t)o * 128 + j] = f2bf(Bexp[(size_t)(j >> 4) * 32768 + (j & 15) * 2048 + o]);
  }
}

// ---------- LoRA-down GEMM: 32x128 tile, 256 blocks, ring-3 + counted vmcnt ----------
__global__ __launch_bounds__(256) void k_gemm_lora(const unsigned short* __restrict__ xb,
                                                   const unsigned short* __restrict__ Ab,
                                                   const float* __restrict__ wrt,
                                                   unsigned short* __restrict__ tmat) {
  __shared__ unsigned short lds[30720];   // 60KB: A 3 bufs x 4KB @0; B 3 x 16KB @12KB
  char* L = (char*)lds;
  const int w = threadIdx.x >> 6, lane = threadIdx.x & 63;
  const int mBase = blockIdx.y * 32;
  const int rl = lane & 15, kq = lane >> 4;
  const unsigned short* aS;
  const unsigned short* bS[4];
  {
    int r  = w * 8 + (lane >> 3);
    int cg = (lane & 7) ^ (r & 7);
    aS = xb + (size_t)(mBase + r) * 2048 + cg * 8;
  }
#pragma unroll
  for (int q = 0; q < 4; ++q) {
    int r  = (w * 4 + q) * 8 + (lane >> 3);
    int cg = (lane & 7) ^ (r & 7);
    bS[q] = Ab + (size_t)r * 2048 + cg * 8;
  }
  const int dA = w * 1024 + lane * 16;

  auto stage = [&](int tau, int buf) {
    if (tau >= 32) return;
    g2lds16(aS + tau * 64, L + buf * 4096 + dA);
#pragma unroll
    for (int q = 0; q < 4; ++q)
      g2lds16(bS[q] + tau * 64, L + 12288 + buf * 16384 + (w * 4 + q) * 1024 + lane * 16);
  };

  f32x4 z = {0.f, 0.f, 0.f, 0.f};
  f32x4 acc[2][2];
#pragma unroll
  for (int i = 0; i < 2; i++)
#pragma unroll
    for (int j = 0; j < 2; j++) acc[i][j] = z;

  stage(0, 0); stage(1, 1);               // 10 ops in flight
  int bR = 0, bSt = 2;

  for (int s = 0; s < 32; ++s) {
    SB();
    if (s < 31) asm volatile("s_waitcnt vmcnt(5)" ::: "memory");
    else        asm volatile("s_waitcnt vmcnt(0)" ::: "memory");
    __builtin_amdgcn_s_barrier(); SB();
    stage(s + 2, bSt);

    const char* lsA = L + bR * 4096;
    const char* lsB = L + 12288 + bR * 16384;
#pragma unroll
    for (int kk = 0; kk < 2; ++kk) {
      bf16x8 af[2], bv[2];
#pragma unroll
      for (int i = 0; i < 2; ++i) {
        int r = i * 16 + rl;
        int c = (kk * 4 + kq) ^ (r & 7);
        af[i] = *(const bf16x8*)(lsA + r * 128 + c * 16);
      }
#pragma unroll
      for (int j = 0; j < 2; ++j) {
        int r = w * 32 + j * 16 + rl;
        int c = (kk * 4 + kq) ^ (r & 7);
        bv[j] = *(const bf16x8*)(lsB + r * 128 + c * 16);
      }
#pragma unroll
      for (int i = 0; i < 2; ++i)
#pragma unroll
        for (int j = 0; j < 2; ++j)
          acc[i][j] = __builtin_amdgcn_mfma_f32_16x16x32_bf16(af[i], bv[j], acc[i][j], 0, 0, 0);
    }
    bR = (bR == 2) ? 0 : bR + 1;
    bSt = (bSt == 2) ? 0 : bSt + 1;
  }
#pragma unroll
  for (int j = 0; j < 2; ++j) {
    int jj = w * 32 + j * 16 + rl;
    int e  = jj >> 4;
#pragma unroll
    for (int i = 0; i < 2; ++i) {
      int m0 = mBase + i * 16 + kq * 4;
#pragma unroll
      for (int q = 0; q < 4; ++q) {
        int m = m0 + q;
        tmat[(size_t)m * 128 + jj] = f2bf(acc[i][j][q] * wrt[(size_t)m * 8 + e]);
      }
    }
  }
}

// ---------- main GEMM: 128x256 tile, BK=32, ring-3 LDS, 2 blocks/CU (R7 exact) ----------
// out = xb.Wb^T (K=2048, tiles 0..63) ++ tmat.Bb^T (K=128, tiles 64..67) + bias
__global__ __launch_bounds__(256, 2) void k_gemm_main(const unsigned short* __restrict__ xb,
                                                      const unsigned short* __restrict__ Wb,
                                                      const unsigned short* __restrict__ tm,
                                                      const unsigned short* __restrict__ Bb,
                                                      const float* __restrict__ bias,
                                                      float* __restrict__ out) {
  __shared__ unsigned short lds[36864];          // 72 KiB: A 3 bufs x 8KB @0; B 3 x 16KB @24KB
  char* L = (char*)lds;
  const int tid = threadIdx.x, wid = tid >> 6, lane = tid & 63;
  const int wm = wid >> 1, wn = wid & 1;         // 2M x 2N waves; wave tile 64 x 128
  const int bid = blockIdx.x;
  const int s = (bid & 7) * 64 + (bid >> 3);     // XCD swizzle (512 = 8*64, bijective)
  const int mBase = (s >> 3) * 128;
  const int nBase = (s & 7) * 256;
  const int rl = lane & 15, kq = lane >> 4;
  // frag offsets: row*64B + chunk*16, chunk = kq ^ ((row>>1)&3)  [0-conflict proven]
  int aOff[4], bOff[8];
#pragma unroll
  for (int i = 0; i < 4; ++i) {
    int r = wm * 64 + i * 16 + rl;
    aOff[i] = r * 64 + ((kq ^ ((r >> 1) & 3)) << 4);
  }
#pragma unroll
  for (int j = 0; j < 8; ++j) {
    int r = wn * 128 + j * 16 + rl;
    bOff[j] = r * 64 + ((kq ^ ((r >> 1) & 3)) << 4);
  }
  // staging: op covers 64 rows x 64B via 256 threads x 16B; linear LDS dest
  const int sRo = tid >> 2;                                    // row within op
  const int sC  = (((tid & 3) ^ ((tid >> 3) & 3)) << 3);       // pre-swizzled src col (elems)

  const unsigned short* aSrc[2];
  const unsigned short* bSrc[4];
#pragma unroll
  for (int o = 0; o < 2; ++o) aSrc[o] = xb + (size_t)(mBase + o * 64 + sRo) * 2048 + sC;
#pragma unroll
  for (int o = 0; o < 4; ++o) bSrc[o] = Wb + (size_t)(nBase + o * 64 + sRo) * 2048 + sC;

  auto stage = [&](int tau, int bufi) {
    if (tau >= 68) return;
    if (tau < 64) {
#pragma unroll
      for (int o = 0; o < 2; ++o) {
        g2lds16(aSrc[o], L + bufi * 8192 + o * 4096 + wid * 1024);
        aSrc[o] += 32;
      }
#pragma unroll
      for (int o = 0; o < 4; ++o) {
        g2lds16(bSrc[o], L + 24576 + bufi * 16384 + o * 4096 + wid * 1024);
        bSrc[o] += 32;
      }
    } else {                                     // K-extension: 4 cold iterations
      int k0 = (tau - 64) * 32;
#pragma unroll
      for (int o = 0; o < 2; ++o)
        g2lds16(tm + (size_t)(mBase + o * 64 + sRo) * 128 + k0 + sC,
                L + bufi * 8192 + o * 4096 + wid * 1024);
#pragma unroll
      for (int o = 0; o < 4; ++o)
        g2lds16(Bb + (size_t)(nBase + o * 64 + sRo) * 128 + k0 + sC,
                L + 24576 + bufi * 16384 + o * 4096 + wid * 1024);
    }
  };

  f32x4 z = {0.f, 0.f, 0.f, 0.f};
  f32x4 acc[4][8];
#pragma unroll
  for (int i = 0; i < 4; ++i)
#pragma unroll
    for (int j = 0; j < 8; ++j) acc[i][j] = z;

  stage(0, 0); stage(1, 1);                      // 12 ops in flight
  int bR = 0, bS = 2;                            // read buf, stage buf

  for (int t = 0; t < 68; ++t) {
    __builtin_amdgcn_sched_barrier(0);
    if (t <= 65) asm volatile("s_waitcnt vmcnt(6)" ::: "memory");   // tile t landed
    else         asm volatile("s_waitcnt vmcnt(0)" ::: "memory");
    __builtin_amdgcn_s_barrier();
    __builtin_amdgcn_sched_barrier(0);
    stage(t + 2, bS);                            // buf (t+2)%3 = (t-1)%3: readers done

    const char* bA = L + bR * 8192;
    const char* bB = L + 24576 + bR * 16384;
    bf16x8 af[4], bv[8];
#pragma unroll
    for (int j = 0; j < 8; ++j) bv[j] = *(const bf16x8*)(bB + bOff[j]);
#pragma unroll
    for (int i = 0; i < 4; ++i) af[i] = *(const bf16x8*)(bA + aOff[i]);
    __builtin_amdgcn_s_setprio(1);
#pragma unroll
    for (int i = 0; i < 4; ++i)
#pragma unroll
      for (int j = 0; j < 8; ++j)
        acc[i][j] = __builtin_amdgcn_mfma_f32_16x16x32_bf16(af[i], bv[j], acc[i][j], 0, 0, 0);
    __builtin_amdgcn_s_setprio(0);

    bR = (bR == 2) ? 0 : bR + 1;
    bS = (bS == 2) ? 0 : bS + 1;
  }

#pragma unroll
  for (int j = 0; j < 8; ++j) {
    int o = nBase + wn * 128 + j * 16 + rl;
    float bb = bias[o];
#pragma unroll
    for (int i = 0; i < 4; ++i) {
      int m0 = mBase + wm * 64 + i * 16 + kq * 4;
#pragma unroll
      for (int q = 0; q < 4; ++q)
        out[(size_t)(m0 + q) * 2048 + o] = acc[i][j][q] + bb;
    }
  }
}

extern "C" void kernel_launch(void* const* d_in, const int* in_sizes, int n_in,
                              void* d_out, int out_size, void* d_ws, size_t ws_size,
                              hipStream_t stream) {
  const float* x    = (const float*)d_in[0];   // (4,2048,2048)
  const float* W    = (const float*)d_in[1];   // (2048,2048)
  const float* bias = (const float*)d_in[2];   // (2048)
  const float* Wr   = (const float*)d_in[3];   // (8,2048)
  const float* A    = (const float*)d_in[4];   // (8,2048,16)
  const float* Bexp = (const float*)d_in[5];   // (8,16,2048)
  float* out = (float*)d_out;

  char* ws = (char*)d_ws;
  unsigned short* xb = (unsigned short*)(ws);                 // 33,554,432 B
  unsigned short* Wb = (unsigned short*)(ws + 33554432);      //  8,388,608 B
  unsigned short* Ab = (unsigned short*)(ws + 41943040);      //    524,288 B
  unsigned short* Bb = (unsigned short*)(ws + 42467328);      //    524,288 B
  unsigned short* tm = (unsigned short*)(ws + 42991616);      //  2,097,152 B
  float*          wr = (float*)(ws + 45088768);               //    262,144 B

  (void)in_sizes; (void)n_in; (void)out_size; (void)ws_size;

  k_pre       <<<dim3(6144), 256, 0, stream>>>(W, A, Bexp, x, Wr, Wb, Ab, Bb, xb, wr);
  k_gemm_lora <<<dim3(1, 256), 256, 0, stream>>>(xb, Ab, wr, tm);
  k_gemm_main <<<dim3(512), 256, 0, stream>>>(xb, Wb, tm, Bb, bias, out);
}

// Round 11
// 112.767 us; speedup vs baseline: 1.5847x; 1.0211x over previous
//
#include <hip/hip_runtime.h>

using f32x4  = __attribute__((ext_vector_type(4))) float;
using bf16x8 = __attribute__((ext_vector_type(8))) __bf16;

#define SB() __builtin_amdgcn_sched_barrier(0)

// ---------- helpers ----------
__device__ __forceinline__ unsigned short f2bf(float f) {
  unsigned int u = __builtin_bit_cast(unsigned int, f);
  u = (u + 0x7FFFu + ((u >> 16) & 1u)) >> 16;   // RNE
  return (unsigned short)u;
}

__device__ __forceinline__ void g2lds16(const void* g, void* l) {
  __builtin_amdgcn_global_load_lds(
      (const __attribute__((address_space(1))) void*)g,
      (__attribute__((address_space(3))) void*)l, 16, 0, 0);
}

// ---------- fused prep: router(LDS-Wr) first, then W cast + A/B repack (R10 exact) ----------
__global__ __launch_bounds__(256) void k_pre(const float* __restrict__ W,
                                             const float* __restrict__ A,
                                             const float* __restrict__ Bexp,
                                             const float* __restrict__ x,
                                             const float* __restrict__ Wr,
                                             unsigned short* __restrict__ Wb,
                                             unsigned short* __restrict__ Ab,
                                             unsigned short* __restrict__ Bb,
                                             unsigned short* __restrict__ xb,
                                             float* __restrict__ wout) {
  __shared__ float swr[8192];             // 32 KB: 4 experts x 2048 f32
  int b = blockIdx.x;
  int tid = threadIdx.x;
  if (b < 2048) {
    // router (f32 exact, Wr via LDS) + x -> bf16 cast; 1 token/wave
    int wvi = tid >> 6, lane = tid & 63;
    int tok = b * 4 + wvi;
    const float4* xr = (const float4*)(x + (size_t)tok * 2048);
    float4 xv[8];
#pragma unroll
    for (int c = 0; c < 8; c++) xv[c] = xr[c * 64 + lane];
    uint2* xbw = (uint2*)(xb + (size_t)tok * 2048);
#pragma unroll
    for (int c = 0; c < 8; c++) {
      uint2 o;
      o.x = (unsigned)f2bf(xv[c].x) | ((unsigned)f2bf(xv[c].y) << 16);
      o.y = (unsigned)f2bf(xv[c].z) | ((unsigned)f2bf(xv[c].w) << 16);
      xbw[c * 64 + lane] = o;
    }
    float lg[8];
#pragma unroll
    for (int half = 0; half < 2; ++half) {
      if (half) __syncthreads();                   // protect previous half's readers
      const float4* src = (const float4*)(Wr + half * 4 * 2048);
#pragma unroll
      for (int i = 0; i < 8; ++i) ((float4*)swr)[i * 256 + tid] = src[i * 256 + tid];
      __syncthreads();
#pragma unroll
      for (int e = 0; e < 4; ++e) {
        const float4* wv4 = (const float4*)(swr + e * 2048);
        float p = 0.f;
#pragma unroll
        for (int c = 0; c < 8; ++c) {
          float4 wv = wv4[c * 64 + lane];
          p += xv[c].x * wv.x + xv[c].y * wv.y + xv[c].z * wv.z + xv[c].w * wv.w;
        }
#pragma unroll
        for (int off = 32; off; off >>= 1) p += __shfl_xor(p, off);
        lg[half * 4 + e] = p;
      }
    }
    int i1 = 0;
#pragma unroll
    for (int e = 1; e < 8; e++) if (lg[e] > lg[i1]) i1 = e;
    int i2 = (i1 == 0) ? 1 : 0;
#pragma unroll
    for (int e = 0; e < 8; e++) { if (e == i1) continue; if (lg[e] > lg[i2]) i2 = e; }
    float e2 = expf(lg[i2] - lg[i1]);
    float den = 1.f + e2;
    if (lane < 8) wout[(size_t)tok * 8 + lane] =
        (lane == i1) ? (1.f / den) : ((lane == i2) ? (e2 / den) : 0.f);
    return;
  }
  if (b < 4096) {                       // W cast: (2048,2048) f32 -> bf16, 8/thread
    int t = (b - 2048) * 256 + tid;
    const float4* p = (const float4*)W;
    float4 a = p[2 * t], c = p[2 * t + 1];
    uint4 o;
    o.x = (unsigned)f2bf(a.x) | ((unsigned)f2bf(a.y) << 16);
    o.y = (unsigned)f2bf(a.z) | ((unsigned)f2bf(a.w) << 16);
    o.z = (unsigned)f2bf(c.x) | ((unsigned)f2bf(c.y) << 16);
    o.w = (unsigned)f2bf(c.z) | ((unsigned)f2bf(c.w) << 16);
    ((uint4*)Wb)[t] = o;
    return;
  }
  if (b < 5120) {                       // A (E,D,R) -> Ab[j=e*16+r][d]
    int t = (b - 4096) * 256 + tid;
    int j = t >> 11, d = t & 2047;
    Ab[t] = f2bf(A[((size_t)(j >> 4) * 2048 + d) * 16 + (j & 15)]);
    return;
  }
  {                                     // Bexp (E,R,O) -> Bb[o][j=e*16+r]
    int t = (b - 5120) * 256 + tid;
    int j = t >> 11, o = t & 2047;
    Bb[(size_t)o * 128 + j] = f2bf(Bexp[(size_t)(j >> 4) * 32768 + (j & 15) * 2048 + o]);
  }
}

// ---------- LoRA-down GEMM: 32x128 tile, 256 blocks, ring-3 + counted vmcnt (R10 exact) ----------
__global__ __launch_bounds__(256) void k_gemm_lora(const unsigned short* __restrict__ xb,
                                                   const unsigned short* __restrict__ Ab,
                                                   const float* __restrict__ wrt,
                                                   unsigned short* __restrict__ tmat) {
  __shared__ unsigned short lds[30720];   // 60KB: A 3 bufs x 4KB @0; B 3 x 16KB @12KB
  char* L = (char*)lds;
  const int w = threadIdx.x >> 6, lane = threadIdx.x & 63;
  const int mBase = blockIdx.y * 32;
  const int rl = lane & 15, kq = lane >> 4;
  const unsigned short* aS;
  const unsigned short* bS[4];
  {
    int r  = w * 8 + (lane >> 3);
    int cg = (lane & 7) ^ (r & 7);
    aS = xb + (size_t)(mBase + r) * 2048 + cg * 8;
  }
#pragma unroll
  for (int q = 0; q < 4; ++q) {
    int r  = (w * 4 + q) * 8 + (lane >> 3);
    int cg = (lane & 7) ^ (r & 7);
    bS[q] = Ab + (size_t)r * 2048 + cg * 8;
  }
  const int dA = w * 1024 + lane * 16;

  auto stage = [&](int tau, int buf) {
    if (tau >= 32) return;
    g2lds16(aS + tau * 64, L + buf * 4096 + dA);
#pragma unroll
    for (int q = 0; q < 4; ++q)
      g2lds16(bS[q] + tau * 64, L + 12288 + buf * 16384 + (w * 4 + q) * 1024 + lane * 16);
  };

  f32x4 z = {0.f, 0.f, 0.f, 0.f};
  f32x4 acc[2][2];
#pragma unroll
  for (int i = 0; i < 2; i++)
#pragma unroll
    for (int j = 0; j < 2; j++) acc[i][j] = z;

  stage(0, 0); stage(1, 1);               // 10 ops in flight
  int bR = 0, bSt = 2;

  for (int s = 0; s < 32; ++s) {
    SB();
    if (s < 31) asm volatile("s_waitcnt vmcnt(5)" ::: "memory");
    else        asm volatile("s_waitcnt vmcnt(0)" ::: "memory");
    __builtin_amdgcn_s_barrier(); SB();
    stage(s + 2, bSt);

    const char* lsA = L + bR * 4096;
    const char* lsB = L + 12288 + bR * 16384;
#pragma unroll
    for (int kk = 0; kk < 2; ++kk) {
      bf16x8 af[2], bv[2];
#pragma unroll
      for (int i = 0; i < 2; ++i) {
        int r = i * 16 + rl;
        int c = (kk * 4 + kq) ^ (r & 7);
        af[i] = *(const bf16x8*)(lsA + r * 128 + c * 16);
      }
#pragma unroll
      for (int j = 0; j < 2; ++j) {
        int r = w * 32 + j * 16 + rl;
        int c = (kk * 4 + kq) ^ (r & 7);
        bv[j] = *(const bf16x8*)(lsB + r * 128 + c * 16);
      }
#pragma unroll
      for (int i = 0; i < 2; ++i)
#pragma unroll
        for (int j = 0; j < 2; ++j)
          acc[i][j] = __builtin_amdgcn_mfma_f32_16x16x32_bf16(af[i], bv[j], acc[i][j], 0, 0, 0);
    }
    bR = (bR == 2) ? 0 : bR + 1;
    bSt = (bSt == 2) ? 0 : bSt + 1;
  }
#pragma unroll
  for (int j = 0; j < 2; ++j) {
    int jj = w * 32 + j * 16 + rl;
    int e  = jj >> 4;
#pragma unroll
    for (int i = 0; i < 2; ++i) {
      int m0 = mBase + i * 16 + kq * 4;
#pragma unroll
      for (int q = 0; q < 4; ++q) {
        int m = m0 + q;
        tmat[(size_t)m * 128 + jj] = f2bf(acc[i][j][q] * wrt[(size_t)m * 8 + e]);
      }
    }
  }
}

// ---------- main GEMM: 256x256 tile, 4 waves (128x128 wave-tile), BK=64, dbuf-2 ----------
// out = xb.Wb^T (K=2048, tiles 0..31) ++ tmat.Bb^T (K=128, tiles 32..33) + bias
__global__ __launch_bounds__(256, 1) void k_gemm_main(const unsigned short* __restrict__ xb,
                                                      const unsigned short* __restrict__ Wb,
                                                      const unsigned short* __restrict__ tm,
                                                      const unsigned short* __restrict__ Bb,
                                                      const float* __restrict__ bias,
                                                      float* __restrict__ out) {
  __shared__ unsigned short lds[65536];          // 128 KiB: A dbuf 2x32KB @0; B @64KB
  char* L = (char*)lds;
  const int tid = threadIdx.x, wid = tid >> 6, lane = tid & 63;
  const int wm = wid >> 1, wn = wid & 1;         // 2x2 waves; wave tile 128x128
  const int bid = blockIdx.x;
  const int s = (bid & 7) * 32 + (bid >> 3);     // XCD swizzle (256 = 8*32, bijective)
  const int mBase = (s >> 3) * 256;              // 32 M-tiles
  const int nBase = (s & 7) * 256;               // 8 N-tiles
  const int rl = lane & 15, kq = lane >> 4;
  // ds_read: 128B rows, chunk c = (ks*4+kq) ^ (row&7); row&7 == rl&7 -> lane-only swizzle
  const int swz0 = ((kq) ^ (rl & 7)) << 4;
  const int swz1 = ((4 + kq) ^ (rl & 7)) << 4;
  const int aB = (wm * 128 + rl) * 128;          // + mi*2048 bytes
  const int bB = (wn * 128 + rl) * 128;          // + nj*2048 bytes
  // staging src (per-lane): row-in-8 = lane>>3, chunk cg = (lane&7)^(lane>>3), elems
  const int sr = lane >> 3;
  const int cg = ((lane & 7) ^ sr) * 8;
  const unsigned short* pA0 = xb + (size_t)(mBase + sr) * 2048 + cg;
  const unsigned short* pB0 = Wb + (size_t)(nBase + sr) * 2048 + cg;
  const unsigned short* qA0 = tm + (size_t)(mBase + sr) * 128 + cg;
  const unsigned short* qB0 = Bb + (size_t)(nBase + sr) * 128 + cg;

  auto stage = [&](int tau) {
    if (tau >= 34) return;
    const int d = (tau & 1) * 32768;
    if (tau < 32) {
      const int k0 = tau * 64;
#pragma unroll
      for (int o = 0; o < 8; ++o) {
        const int rb = o * 4 + wid;              // row-block 0..31 (8 rows each)
        g2lds16(pA0 + (size_t)rb * 16384 + k0, L + d + rb * 1024);
        g2lds16(pB0 + (size_t)rb * 16384 + k0, L + 65536 + d + rb * 1024);
      }
    } else {
      const int k0 = (tau - 32) * 64;
#pragma unroll
      for (int o = 0; o < 8; ++o) {
        const int rb = o * 4 + wid;
        g2lds16(qA0 + (size_t)rb * 1024 + k0, L + d + rb * 1024);
        g2lds16(qB0 + (size_t)rb * 1024 + k0, L + 65536 + d + rb * 1024);
      }
    }
  };

  f32x4 z = {0.f, 0.f, 0.f, 0.f};
  f32x4 acc[8][8];
#pragma unroll
  for (int i = 0; i < 8; ++i)
#pragma unroll
    for (int j = 0; j < 8; ++j) acc[i][j] = z;

  stage(0);                                      // 16 ops in flight

  for (int t = 0; t < 34; ++t) {
    SB();
    __builtin_amdgcn_s_barrier();                // all waves done reading buf (t+1)&1
    SB();
    stage(t + 1);                                // 16 more ops -> 32 outstanding
    SB();
    if (t < 33) asm volatile("s_waitcnt vmcnt(16)" ::: "memory");   // tile t landed
    else        asm volatile("s_waitcnt vmcnt(0)" ::: "memory");
    SB();
    const char* bufA = L + (t & 1) * 32768;
    const char* bufB = L + 65536 + (t & 1) * 32768;
    bf16x8 af[8], bv[8];
    // ---- k-slice 0
#pragma unroll
    for (int mi = 0; mi < 8; ++mi) af[mi] = *(const bf16x8*)(bufA + aB + mi * 2048 + swz0);
#pragma unroll
    for (int nj = 0; nj < 8; ++nj) bv[nj] = *(const bf16x8*)(bufB + bB + nj * 2048 + swz0);
    __builtin_amdgcn_s_setprio(1);
#pragma unroll
    for (int mi = 0; mi < 8; ++mi)
#pragma unroll
      for (int nj = 0; nj < 8; ++nj)
        acc[mi][nj] = __builtin_amdgcn_mfma_f32_16x16x32_bf16(af[mi], bv[nj], acc[mi][nj], 0, 0, 0);
    __builtin_amdgcn_s_setprio(0);
    // ---- k-slice 1
#pragma unroll
    for (int mi = 0; mi < 8; ++mi) af[mi] = *(const bf16x8*)(bufA + aB + mi * 2048 + swz1);
#pragma unroll
    for (int nj = 0; nj < 8; ++nj) bv[nj] = *(const bf16x8*)(bufB + bB + nj * 2048 + swz1);
    __builtin_amdgcn_s_setprio(1);
#pragma unroll
    for (int mi = 0; mi < 8; ++mi)
#pragma unroll
      for (int nj = 0; nj < 8; ++nj)
        acc[mi][nj] = __builtin_amdgcn_mfma_f32_16x16x32_bf16(af[mi], bv[nj], acc[mi][nj], 0, 0, 0);
    __builtin_amdgcn_s_setprio(0);
  }

#pragma unroll
  for (int nj = 0; nj < 8; ++nj) {
    int o = nBase + wn * 128 + nj * 16 + rl;
    float bb = bias[o];
#pragma unroll
    for (int mi = 0; mi < 8; ++mi) {
      int m0 = mBase + wm * 128 + mi * 16 + kq * 4;
#pragma unroll
      for (int q = 0; q < 4; ++q)
        out[(size_t)(m0 + q) * 2048 + o] = acc[mi][nj][q] + bb;
    }
  }
}

extern "C" void kernel_launch(void* const* d_in, const int* in_sizes, int n_in,
                              void* d_out, int out_size, void* d_ws, size_t ws_size,
                              hipStream_t stream) {
  const float* x    = (const float*)d_in[0];   // (4,2048,2048)
  const float* W    = (const float*)d_in[1];   // (2048,2048)
  const float* bias = (const float*)d_in[2];   // (2048)
  const float* Wr   = (const float*)d_in[3];   // (8,2048)
  const float* A    = (const float*)d_in[4];   // (8,2048,16)
  const float* Bexp = (const float*)d_in[5];   // (8,16,2048)
  float* out = (float*)d_out;

  char* ws = (char*)d_ws;
  unsigned short* xb = (unsigned short*)(ws);                 // 33,554,432 B
  unsigned short* Wb = (unsigned short*)(ws + 33554432);      //  8,388,608 B
  unsigned short* Ab = (unsigned short*)(ws + 41943040);      //    524,288 B
  unsigned short* Bb = (unsigned short*)(ws + 42467328);      //    524,288 B
  unsigned short* tm = (unsigned short*)(ws + 42991616);      //  2,097,152 B
  float*          wr = (float*)(ws + 45088768);               //    262,144 B

  (void)in_sizes; (void)n_in; (void)out_size; (void)ws_size;

  k_pre       <<<dim3(6144), 256, 0, stream>>>(W, A, Bexp, x, Wr, Wb, Ab, Bb, xb, wr);
  k_gemm_lora <<<dim3(1, 256), 256, 0, stream>>>(xb, Ab, wr, tm);
  k_gemm_main <<<dim3(256), 256, 0, stream>>>(xb, Wb, tm, Bb, bias, out);
}